// Round 18
// baseline (294.446 us; speedup 1.0000x reference)
//
#include <hip/hip_runtime.h>
#include <hip/hip_fp16.h>
#include <cstdint>
#include <cstddef>

#define B_ 512
#define T_ 256
#define N_ 128
#define H_ 64
#define G_ 256  // 4H

typedef __attribute__((ext_vector_type(8))) short short8;
typedef __attribute__((ext_vector_type(4))) float f32x4;
typedef _Float16 half2_t __attribute__((ext_vector_type(2)));

static __device__ __forceinline__ unsigned short f2bf(float f) {
    union { float f; unsigned int i; } v;
    v.f = f;
    unsigned int x = v.i;
    return (unsigned short)((x + 0x7fffu + ((x >> 16) & 1u)) >> 16);  // RNE
}
static __device__ __forceinline__ half2_t u2h2(unsigned int u) {
    union { unsigned int u; half2_t h; } v; v.u = u; return v.h;
}

// ---------------------------------------------------------------------------
// K0: pack W_hh (f32 [4H][H]) -> wpack uint4 [4][8][64]: wpack[g][q][j] =
// half2x4 of W_hh[g*64+j][8q..8q+7].  Per-lane order for k_rnn16's asm loads.
// ---------------------------------------------------------------------------
__global__ __launch_bounds__(256) void k_wpack(const float* __restrict__ W_hh,
                                               uint4* __restrict__ wpack) {
    int idx = blockIdx.x * 256 + threadIdx.x;   // 2048 entries
    if (idx >= 2048) return;
    int g = idx >> 9, q = (idx >> 6) & 7, j = idx & 63;
    const float* src = W_hh + ((size_t)(g * H_ + j)) * H_ + q * 8;
    float4 a = *(const float4*)(src);
    float4 b = *(const float4*)(src + 4);
    union { uint4 u; half2_t h[4]; } pk;
    pk.h[0] = (half2_t){(_Float16)a.x, (_Float16)a.y};
    pk.h[1] = (half2_t){(_Float16)a.z, (_Float16)a.w};
    pk.h[2] = (half2_t){(_Float16)b.x, (_Float16)b.y};
    pk.h[3] = (half2_t){(_Float16)b.z, (_Float16)b.w};
    wpack[idx] = pk.u;
}

// ---------------------------------------------------------------------------
// K1+K2 fused (unchanged: ~48us). gatesx layout: [b][t][cell][gate i,f,g,o].
// ---------------------------------------------------------------------------
__global__ __launch_bounds__(256) void k_awgemm(const float* __restrict__ x,
                                                const float* __restrict__ attn_w,
                                                const float* __restrict__ W_ih,
                                                const float* __restrict__ b_ih,
                                                const float* __restrict__ b_hh,
                                                float* __restrict__ iw,
                                                _Float16* __restrict__ gatesx) {
    __shared__ __align__(16) unsigned short Wl[G_][136];  // bf16 W_ih, padded
    __shared__ __align__(16) unsigned short Al[32][136];  // bf16 wx tile (overlaid: red)
    __shared__ float bias[G_];
    __shared__ float aw_s[T_];
    __shared__ float a_s[N_];
    __shared__ float wred[4];
    const int tid = threadIdx.x;
    const int b = blockIdx.x;

    for (int q = tid; q < G_ * 32; q += 256) {
        int r = q >> 5, c4 = (q & 31) << 2;
        float4 v = *(const float4*)(W_ih + r * N_ + c4);
        Wl[r][c4 + 0] = f2bf(v.x); Wl[r][c4 + 1] = f2bf(v.y);
        Wl[r][c4 + 2] = f2bf(v.z); Wl[r][c4 + 3] = f2bf(v.w);
    }
    bias[tid] = b_ih[tid] + b_hh[tid];
    aw_s[tid] = attn_w[2 * H_ + tid];
    __syncthreads();

    // ---- Phase A: attention softmax (shift-invariance kills h/c/bias) ----
    float (*red)[128] = (float(*)[128])&Al[0][0];
    const int n0 = (tid & 31) << 2;
    const int tg = tid >> 5;
    const float* xb = x + (size_t)b * (T_ * N_);
    {
        float p0 = 0.f, p1 = 0.f, p2 = 0.f, p3 = 0.f;
        for (int t = tg; t < T_; t += 8) {
            float4 v = *(const float4*)(xb + t * N_ + n0);
            float w = aw_s[t];
            p0 += v.x * w; p1 += v.y * w; p2 += v.z * w; p3 += v.w * w;
        }
        red[tg][n0 + 0] = p0; red[tg][n0 + 1] = p1;
        red[tg][n0 + 2] = p2; red[tg][n0 + 3] = p3;
    }
    __syncthreads();
    {
        float s = 0.f;
        if (tid < 128) {
            #pragma unroll
            for (int g = 0; g < 8; ++g) s += red[g][tid];
        }
        float m = (tid < 128) ? s : -1e30f;
        #pragma unroll
        for (int d = 1; d < 64; d <<= 1) m = fmaxf(m, __shfl_xor(m, d));
        if ((tid & 63) == 0) wred[tid >> 6] = m;
        __syncthreads();
        m = fmaxf(wred[0], wred[1]);
        __syncthreads();
        float e = (tid < 128) ? __expf(s - m) : 0.f;
        float z = e;
        #pragma unroll
        for (int d = 1; d < 64; d <<= 1) z += __shfl_xor(z, d);
        if ((tid & 63) == 0) wred[tid >> 6] = z;
        __syncthreads();
        z = wred[0] + wred[1];
        if (tid < 128) a_s[tid] = e / z;
    }
    __syncthreads();

    // ---- Phase B: weighting + MFMA GEMM ----
    const int lane = tid & 63;
    const int lr = lane & 15;
    const int lk = (lane >> 4) << 3;
    const int gc0 = (tid >> 6) << 6;
    const int orow = (lane >> 4) << 2;

    for (int st = 0; st < 8; ++st) {
        const int r0 = b * T_ + st * 32;
        __syncthreads();
        for (int q = tid; q < 32 * 32; q += 256) {
            int r = q >> 5, c4 = (q & 31) << 2;
            size_t off = (size_t)(r0 + r) * N_ + c4;
            float4 v = *(const float4*)(x + off);
            float4 w;
            w.x = a_s[c4 + 0] * v.x; w.y = a_s[c4 + 1] * v.y;
            w.z = a_s[c4 + 2] * v.z; w.w = a_s[c4 + 3] * v.w;
            *(float4*)(iw + off) = w;            // output 0 (f32, exact)
            Al[r][c4 + 0] = f2bf(w.x); Al[r][c4 + 1] = f2bf(w.y);
            Al[r][c4 + 2] = f2bf(w.z); Al[r][c4 + 3] = f2bf(w.w);
        }
        __syncthreads();

        f32x4 acc[2][4];
        #pragma unroll
        for (int mt = 0; mt < 2; ++mt)
            #pragma unroll
            for (int nt = 0; nt < 4; ++nt)
                acc[mt][nt] = (f32x4){0.f, 0.f, 0.f, 0.f};

        #pragma unroll
        for (int kk = 0; kk < N_; kk += 32) {
            short8 af0 = *(const short8*)(&Al[lr][kk + lk]);
            short8 af1 = *(const short8*)(&Al[16 + lr][kk + lk]);
            #pragma unroll
            for (int nt = 0; nt < 4; ++nt) {
                short8 bfv = *(const short8*)(&Wl[gc0 + nt * 16 + lr][kk + lk]);
                acc[0][nt] = __builtin_amdgcn_mfma_f32_16x16x32_bf16(af0, bfv, acc[0][nt], 0, 0, 0);
                acc[1][nt] = __builtin_amdgcn_mfma_f32_16x16x32_bf16(af1, bfv, acc[1][nt], 0, 0, 0);
            }
        }
        // D: col = gc0+nt*16+lr (gate index), row = mt*16+(lane>>4)*4+reg
        #pragma unroll
        for (int mt = 0; mt < 2; ++mt) {
            #pragma unroll
            for (int nt = 0; nt < 4; ++nt) {
                int col = gc0 + nt * 16 + lr;
                float bs = bias[col];
                int cell = col & 63, qg = col >> 6;
                #pragma unroll
                for (int rg = 0; rg < 4; ++rg) {
                    int rr = r0 + mt * 16 + orow + rg;
                    gatesx[((size_t)rr * H_ + cell) * 4 + qg] =
                        (_Float16)(acc[mt][nt][rg] + bs);
                }
            }
        }
    }
}

// ---------------------------------------------------------------------------
// K3: LSTM recurrence — k_rnn7 per-wave logic VERBATIM, but 8 independent
// waves per block (one batch each) -> 2 waves per SIMD.
// Round-17 analysis: the 133us/1250cy-step invariant decomposes as ~400cy
// issue (VALUBusy 35% x 2cy/inst) + ~850cy dependency latency on a SOLO
// wave/SIMD with nothing to fill it. Six in-wave restructures failed; the
// untested lever is CO-RESIDENT waves: the HW wave scheduler interleaves
// two independent recurrences on one SIMD (immune to compiler regalloc
// de-interleaving that killed round 10). 64 blocks x 512 thr = 8 waves on
// 4 SIMDs = 2/SIMD. waves_per_eu(2,2) pins VGPR budget at 256 (no spill --
// round-16 trap). Zero LDS, zero barriers: waves fully independent.
// ---------------------------------------------------------------------------
__global__ __attribute__((amdgpu_flat_work_group_size(512, 512)))
__attribute__((amdgpu_waves_per_eu(2, 2)))
void k_rnn16(const _Float16* __restrict__ gatesx,
             const uint4* __restrict__ wpack,
             float* __restrict__ enc) {
    const int j = threadIdx.x & 63;            // cell index
    const int b = blockIdx.x * 8 + (threadIdx.x >> 6);   // one batch per wave

    // 32 x dwordx4 = 128 VGPRs of packed half2 weights (4 gate rows x 8 quads)
    uint4 wv[4][8];
    #pragma unroll
    for (int g = 0; g < 4; ++g) {
        #pragma unroll
        for (int q = 0; q < 8; ++q) {
            unsigned voff = (unsigned)((((g << 3) + q) * 64 + j) << 4);
            asm volatile("global_load_dwordx4 %0, %1, %2"
                         : "=v"(wv[g][q]) : "v"(voff), "s"(wpack) : "memory");
        }
    }
    asm volatile("s_waitcnt vmcnt(0)" ::: "memory");

    float c = 0.f;
    unsigned hpk = 0u;                 // lane-pair packed f16 (h[2m], h[2m+1]); h_{-1}=0
    const bool even = ((j & 1) == 0);

    const _Float16* gx = gatesx + ((size_t)b * T_ * H_ + j) * 4;
    float* ep = enc + (size_t)b * T_ * H_ + j;

    uint2 gA = *(const uint2*)(gx);            // t = 0
    uint2 gB = *(const uint2*)(gx + G_);       // t = 1

#define DOT_STEP(m, c0, c1, c2, c3)                                         \
        do {                                                                \
            unsigned hs_ = (unsigned)__builtin_amdgcn_readlane((int)hpk, 2 * (m)); \
            half2_t hh_ = u2h2(hs_);                                        \
            a0 = __builtin_amdgcn_fdot2(u2h2(c0), hh_, a0, false);          \
            a1 = __builtin_amdgcn_fdot2(u2h2(c1), hh_, a1, false);          \
            a2 = __builtin_amdgcn_fdot2(u2h2(c2), hh_, a2, false);          \
            a3 = __builtin_amdgcn_fdot2(u2h2(c3), hh_, a3, false);          \
        } while (0)

#define STEP(GREG, TNEXT)                                                   \
    {                                                                       \
        half2_t gif = u2h2(GREG.x), ggo = u2h2(GREG.y);                     \
        float a0 = (float)gif.x, a1 = (float)gif.y;                         \
        float a2 = (float)ggo.x, a3 = (float)ggo.y;                         \
        int tn_ = (TNEXT) < T_ ? (TNEXT) : (T_ - 1);                        \
        GREG = *(const uint2*)(gx + (size_t)tn_ * G_);                      \
        _Pragma("unroll")                                                   \
        for (int q = 0; q < 8; ++q) {                                       \
            DOT_STEP(4 * q + 0, wv[0][q].x, wv[1][q].x, wv[2][q].x, wv[3][q].x); \
            DOT_STEP(4 * q + 1, wv[0][q].y, wv[1][q].y, wv[2][q].y, wv[3][q].y); \
            DOT_STEP(4 * q + 2, wv[0][q].z, wv[1][q].z, wv[2][q].z, wv[3][q].z); \
            DOT_STEP(4 * q + 3, wv[0][q].w, wv[1][q].w, wv[2][q].w, wv[3][q].w); \
        }                                                                   \
        float si = 1.f / (1.f + __expf(-a0));                               \
        float sf = 1.f / (1.f + __expf(-a1));                               \
        float tg = 1.f - 2.f / (__expf(2.f * a2) + 1.f);                    \
        float so = 1.f / (1.f + __expf(-a3));                               \
        c = sf * c + si * tg;                                               \
        float tc = 1.f - 2.f / (__expf(2.f * c) + 1.f);                     \
        float h = so * tc;                                                  \
        union { _Float16 hf; unsigned short u; } cv_; cv_.hf = (_Float16)h; \
        unsigned hf_ = cv_.u;                                               \
        unsigned nb_ = (unsigned)__builtin_amdgcn_mov_dpp((int)hf_, 0xB1, 0xF, 0xF, true); \
        hpk = even ? (hf_ | (nb_ << 16)) : (nb_ | (hf_ << 16));             \
        *ep = h;                                                            \
        ep += H_;                                                           \
    }

    for (int t = 0; t < T_; t += 2) {
        STEP(gA, t + 2);
        STEP(gB, t + 3);
    }
#undef STEP
#undef DOT_STEP
}

extern "C" void kernel_launch(void* const* d_in, const int* in_sizes, int n_in,
                              void* d_out, int out_size, void* d_ws, size_t ws_size,
                              hipStream_t stream) {
    if (n_in < 7 || in_sizes[0] != B_ * T_ * N_) return;

    const float* x    = (const float*)d_in[0];
    const float* aw   = (const float*)d_in[1];
    // d_in[2] (attn_b) provably cancels in the softmax — unused.
    const float* W_ih = (const float*)d_in[3];
    const float* W_hh = (const float*)d_in[4];
    const float* b_ih = (const float*)d_in[5];
    const float* b_hh = (const float*)d_in[6];

    float* iwp = (float*)d_out;                          // (B,T,N) f32
    float* enc = (float*)d_out + (size_t)B_ * T_ * N_;   // (B,T,H) f32

    size_t gx_bytes = (size_t)B_ * T_ * G_ * sizeof(_Float16);   // 33.5 MB
    _Float16* gatesx = (_Float16*)d_ws;
    uint4* wpack = (uint4*)((char*)d_ws + gx_bytes);             // 32 KB
    size_t need = gx_bytes + 2048 * sizeof(uint4);
    if (ws_size < need) return;  // fail loudly rather than corrupt

    hipLaunchKernelGGL(k_wpack, dim3(8), dim3(256), 0, stream, W_hh, wpack);
    hipLaunchKernelGGL(k_awgemm, dim3(B_), dim3(256), 0, stream,
                       x, aw, W_ih, b_ih, b_hh, iwp, gatesx);
    hipLaunchKernelGGL(k_rnn16, dim3(B_ / 8), dim3(512), 0, stream,
                       gatesx, wpack, enc);
}

// Round 20
// 177.649 us; speedup vs baseline: 1.6575x; 1.6575x over previous
//
#include <hip/hip_runtime.h>
#include <hip/hip_fp16.h>
#include <cstdint>
#include <cstddef>

#define B_ 512
#define T_ 256
#define N_ 128
#define H_ 64
#define G_ 256  // 4H

typedef __attribute__((ext_vector_type(8))) short short8;
typedef __attribute__((ext_vector_type(4))) float f32x4;
typedef _Float16 half2_t __attribute__((ext_vector_type(2)));

static __device__ __forceinline__ float bf2f(unsigned short u) {
    union { unsigned int i; float f; } v;
    v.i = ((unsigned int)u) << 16;
    return v.f;
}
static __device__ __forceinline__ unsigned short f2bf(float f) {
    union { float f; unsigned int i; } v;
    v.f = f;
    unsigned int x = v.i;
    return (unsigned short)((x + 0x7fffu + ((x >> 16) & 1u)) >> 16);  // RNE
}
static __device__ __forceinline__ half2_t u2h2(unsigned int u) {
    union { unsigned int u; half2_t h; } v; v.u = u; return v.h;
}

// ---------------------------------------------------------------------------
// K0a: pack W_hh (f32 [4H][H]) -> wpack uint4 [4][8][64] (k_rnn10 lane order).
// ---------------------------------------------------------------------------
__global__ __launch_bounds__(256) void k_wpack(const float* __restrict__ W_hh,
                                               uint4* __restrict__ wpack) {
    int idx = blockIdx.x * 256 + threadIdx.x;   // 2048 entries
    if (idx >= 2048) return;
    int g = idx >> 9, q = (idx >> 6) & 7, j = idx & 63;
    const float* src = W_hh + ((size_t)(g * H_ + j)) * H_ + q * 8;
    float4 a = *(const float4*)(src);
    float4 b = *(const float4*)(src + 4);
    union { uint4 u; half2_t h[4]; } pk;
    pk.h[0] = (half2_t){(_Float16)a.x, (_Float16)a.y};
    pk.h[1] = (half2_t){(_Float16)a.z, (_Float16)a.w};
    pk.h[2] = (half2_t){(_Float16)b.x, (_Float16)b.y};
    pk.h[3] = (half2_t){(_Float16)b.z, (_Float16)b.w};
    wpack[idx] = pk.u;
}

// ---------------------------------------------------------------------------
// K0b: pack W_ih -> bf16 MFMA B-fragments, per-lane order for k_awgemm2.
// ROUND-19 BUG FIX: needs 4096 entries (w,nt,kc,lane = 4*4*4*64), was
// launched with only 1024 -> waves 1..3 (gates f,g,o) read poisoned ws
// (~zero weights) -> enc absmax 2.1e-2. Now: 16 blocks, 64 KB.
// Entry idx = (w*16 + nt*4 + kc)*64 + lane holds short8{ bf16(
//   W_ih[w*64 + nt*16 + (lane&15)][kc*32 + (lane>>4)*8 + e] ) }, e=0..7.
// ---------------------------------------------------------------------------
__global__ __launch_bounds__(256) void k_wpackIH(const float* __restrict__ W_ih,
                                                 uint4* __restrict__ wp) {
    int idx = blockIdx.x * 256 + threadIdx.x;   // 4096 entries x 16B = 64 KB
    if (idx >= 4096) return;
    int lane = idx & 63;
    int rest = idx >> 6;            // w*16 + nt*4 + kc, 0..63
    int kc = rest & 3, nt = (rest >> 2) & 3, w = rest >> 4;
    int row = w * 64 + nt * 16 + (lane & 15);
    int kb  = kc * 32 + (lane >> 4) * 8;
    const float* src = W_ih + (size_t)row * N_ + kb;
    union { uint4 u; unsigned short s[8]; } pk;
    #pragma unroll
    for (int e = 0; e < 8; ++e) pk.s[e] = f2bf(src[e]);
    wp[idx] = pk.u;
}

// ---------------------------------------------------------------------------
// K1+K2: attention + weighting + GEMM, traffic-optimized (round-18 design,
// round-19 pack-size bug fixed + explicit vmcnt drain for the asm loads).
//  - x staged to LDS as bf16 during Phase A (no Phase-B global x re-read).
//  - W_ih fragments in 64 registers (asm loads + waves_per_eu(2,2)).
//  - LDS ~76 KB -> 2 blocks/CU; in-place weighting; 1 barrier/subtile.
// HBM: read x 67 + write iw 67 + write gatesx 33.5 = 167.5 MB ~= 27us floor.
// ---------------------------------------------------------------------------
__global__ __attribute__((amdgpu_flat_work_group_size(256, 256)))
__attribute__((amdgpu_waves_per_eu(2, 2)))
void k_awgemm2(const float* __restrict__ x,
               const float* __restrict__ attn_w,
               const uint4* __restrict__ wih,
               const float* __restrict__ b_ih,
               const float* __restrict__ b_hh,
               float* __restrict__ iw,
               _Float16* __restrict__ gatesx) {
    __shared__ __align__(16) unsigned short Xl[T_][136];  // bf16 x / wx, padded
    __shared__ float red2[8][128];
    __shared__ float bias[G_];
    __shared__ float aw_s[T_];
    __shared__ float a_s[N_];
    __shared__ float wred[4];
    const int tid = threadIdx.x;
    const int b = blockIdx.x;
    const int lane = tid & 63;
    const int w = tid >> 6;

    // W_ih B-fragments: 16 x asm dwordx4 = 64 forced-live VGPRs
    uint4 bfw[4][4];   // [nt][kc]
    #pragma unroll
    for (int nt = 0; nt < 4; ++nt) {
        #pragma unroll
        for (int kc = 0; kc < 4; ++kc) {
            unsigned voff = (unsigned)((((w * 4 + nt) * 4 + kc) * 64 + lane) << 4);
            asm volatile("global_load_dwordx4 %0, %1, %2"
                         : "=v"(bfw[nt][kc]) : "v"(voff), "s"(wih) : "memory");
        }
    }
    asm volatile("s_waitcnt vmcnt(0)" ::: "memory");   // asm loads invisible to
                                                       // the waitcnt pass: drain

    bias[tid] = b_ih[tid] + b_hh[tid];
    aw_s[tid] = attn_w[2 * H_ + tid];
    __syncthreads();

    // ---- Phase A: attention dot + softmax; stage x -> Xl (bf16) ----
    const int n0 = (tid & 31) << 2;
    const int tg = tid >> 5;
    const float* xb = x + (size_t)b * (T_ * N_);
    {
        float p0 = 0.f, p1 = 0.f, p2 = 0.f, p3 = 0.f;
        for (int t = tg; t < T_; t += 8) {
            float4 v = *(const float4*)(xb + t * N_ + n0);
            float wt = aw_s[t];
            p0 += v.x * wt; p1 += v.y * wt; p2 += v.z * wt; p3 += v.w * wt;
            Xl[t][n0 + 0] = f2bf(v.x); Xl[t][n0 + 1] = f2bf(v.y);
            Xl[t][n0 + 2] = f2bf(v.z); Xl[t][n0 + 3] = f2bf(v.w);
        }
        red2[tg][n0 + 0] = p0; red2[tg][n0 + 1] = p1;
        red2[tg][n0 + 2] = p2; red2[tg][n0 + 3] = p3;
    }
    __syncthreads();
    {
        float s = 0.f;
        if (tid < 128) {
            #pragma unroll
            for (int g = 0; g < 8; ++g) s += red2[g][tid];
        }
        float m = (tid < 128) ? s : -1e30f;
        #pragma unroll
        for (int d = 1; d < 64; d <<= 1) m = fmaxf(m, __shfl_xor(m, d));
        if ((tid & 63) == 0) wred[tid >> 6] = m;
        __syncthreads();
        m = fmaxf(wred[0], wred[1]);
        __syncthreads();
        float e = (tid < 128) ? __expf(s - m) : 0.f;
        float z = e;
        #pragma unroll
        for (int d = 1; d < 64; d <<= 1) z += __shfl_xor(z, d);
        if ((tid & 63) == 0) wred[tid >> 6] = z;
        __syncthreads();
        z = wred[0] + wred[1];
        if (tid < 128) a_s[tid] = e / z;
    }
    __syncthreads();   // a_s + all Xl writes visible

    // ---- Phase B: in-place weighting + MFMA (B from registers) ----
    const int lr = lane & 15;
    const int lk = (lane >> 4) << 3;
    const int gc0 = w << 6;
    const int orow = (lane >> 4) << 2;

    for (int st = 0; st < 8; ++st) {
        const int r0g = b * T_ + st * 32;
        // weight rows st*32..+31 in place (each elem read+written by 1 thread)
        for (int q = tid; q < 32 * 32; q += 256) {
            int r = q >> 5, c4 = (q & 31) << 2;
            int row = st * 32 + r;
            ushort4 xv = *(const ushort4*)(&Xl[row][c4]);
            float4 wv4;
            wv4.x = a_s[c4 + 0] * bf2f(xv.x); wv4.y = a_s[c4 + 1] * bf2f(xv.y);
            wv4.z = a_s[c4 + 2] * bf2f(xv.z); wv4.w = a_s[c4 + 3] * bf2f(xv.w);
            *(float4*)(iw + (size_t)(r0g + r) * N_ + c4) = wv4;   // output 0
            Xl[row][c4 + 0] = f2bf(wv4.x); Xl[row][c4 + 1] = f2bf(wv4.y);
            Xl[row][c4 + 2] = f2bf(wv4.z); Xl[row][c4 + 3] = f2bf(wv4.w);
        }
        __syncthreads();   // wx(st) visible; next-st weighting is disjoint rows

        f32x4 acc[2][4];
        #pragma unroll
        for (int mt = 0; mt < 2; ++mt)
            #pragma unroll
            for (int nt = 0; nt < 4; ++nt)
                acc[mt][nt] = (f32x4){0.f, 0.f, 0.f, 0.f};

        #pragma unroll
        for (int kc = 0; kc < 4; ++kc) {
            short8 af0 = *(const short8*)(&Xl[st * 32 + lr][kc * 32 + lk]);
            short8 af1 = *(const short8*)(&Xl[st * 32 + 16 + lr][kc * 32 + lk]);
            #pragma unroll
            for (int nt = 0; nt < 4; ++nt) {
                short8 bfv = *(const short8*)(&bfw[nt][kc]);
                acc[0][nt] = __builtin_amdgcn_mfma_f32_16x16x32_bf16(af0, bfv, acc[0][nt], 0, 0, 0);
                acc[1][nt] = __builtin_amdgcn_mfma_f32_16x16x32_bf16(af1, bfv, acc[1][nt], 0, 0, 0);
            }
        }
        // D: col = gc0+nt*16+lr (gate), row = mt*16+orow+rg ; quad layout out
        #pragma unroll
        for (int mt = 0; mt < 2; ++mt) {
            #pragma unroll
            for (int nt = 0; nt < 4; ++nt) {
                int col = gc0 + nt * 16 + lr;
                float bs = bias[col];
                int cell = col & 63, qg = col >> 6;
                #pragma unroll
                for (int rg = 0; rg < 4; ++rg) {
                    int rr = r0g + mt * 16 + orow + rg;
                    gatesx[((size_t)rr * H_ + cell) * 4 + qg] =
                        (_Float16)(acc[mt][nt][rg] + bs);
                }
            }
        }
    }
}

// ---------------------------------------------------------------------------
// K3: LSTM recurrence — k_rnn10 VERBATIM (best: 133us). Single-wave blocks,
// zero barriers; asm-resident W_hh + waves_per_eu(1,1); uniform ds_read
// h-broadcast; depth-2 named prefetch.
// ---------------------------------------------------------------------------
__global__ __attribute__((amdgpu_flat_work_group_size(64, 64)))
__attribute__((amdgpu_waves_per_eu(1, 1)))
void k_rnn10(const _Float16* __restrict__ gatesx,
             const uint4* __restrict__ wpack,
             float* __restrict__ enc) {
    __shared__ __align__(16) _Float16 hs[H_];   // h_t (f16), 128 B
    const int j = threadIdx.x;   // cell index
    const int b = blockIdx.x;

    uint4 wv[4][8];
    #pragma unroll
    for (int g = 0; g < 4; ++g) {
        #pragma unroll
        for (int q = 0; q < 8; ++q) {
            unsigned voff = (unsigned)((((g << 3) + q) * 64 + j) << 4);
            asm volatile("global_load_dwordx4 %0, %1, %2"
                         : "=v"(wv[g][q]) : "v"(voff), "s"(wpack) : "memory");
        }
    }
    asm volatile("s_waitcnt vmcnt(0)" ::: "memory");

    hs[j] = (_Float16)0.f;     // h_{-1} = 0 (single wave: DS in-order)
    float c = 0.f;

    const _Float16* gx = gatesx + ((size_t)b * T_ * H_ + j) * 4;
    float* ep = enc + (size_t)b * T_ * H_ + j;

    uint2 gA = *(const uint2*)(gx);            // t = 0
    uint2 gB = *(const uint2*)(gx + G_);       // t = 1

#define STEP(GREG, TNEXT)                                                   \
    {                                                                       \
        half2_t gif = u2h2(GREG.x), ggo = u2h2(GREG.y);                     \
        float a0 = (float)gif.x, a1 = (float)gif.y;                         \
        float a2 = (float)ggo.x, a3 = (float)ggo.y;                         \
        int tn_ = (TNEXT) < T_ ? (TNEXT) : (T_ - 1);                        \
        GREG = *(const uint2*)(gx + (size_t)tn_ * G_);                      \
        const uint4* hv4 = (const uint4*)hs;                                \
        _Pragma("unroll")                                                   \
        for (int q = 0; q < 8; ++q) {                                       \
            uint4 ch = hv4[q];        /* uniform addr -> broadcast */       \
            a0 = __builtin_amdgcn_fdot2(u2h2(wv[0][q].x), u2h2(ch.x), a0, false); \
            a1 = __builtin_amdgcn_fdot2(u2h2(wv[1][q].x), u2h2(ch.x), a1, false); \
            a2 = __builtin_amdgcn_fdot2(u2h2(wv[2][q].x), u2h2(ch.x), a2, false); \
            a3 = __builtin_amdgcn_fdot2(u2h2(wv[3][q].x), u2h2(ch.x), a3, false); \
            a0 = __builtin_amdgcn_fdot2(u2h2(wv[0][q].y), u2h2(ch.y), a0, false); \
            a1 = __builtin_amdgcn_fdot2(u2h2(wv[1][q].y), u2h2(ch.y), a1, false); \
            a2 = __builtin_amdgcn_fdot2(u2h2(wv[2][q].y), u2h2(ch.y), a2, false); \
            a3 = __builtin_amdgcn_fdot2(u2h2(wv[3][q].y), u2h2(ch.y), a3, false); \
            a0 = __builtin_amdgcn_fdot2(u2h2(wv[0][q].z), u2h2(ch.z), a0, false); \
            a1 = __builtin_amdgcn_fdot2(u2h2(wv[1][q].z), u2h2(ch.z), a1, false); \
            a2 = __builtin_amdgcn_fdot2(u2h2(wv[2][q].z), u2h2(ch.z), a2, false); \
            a3 = __builtin_amdgcn_fdot2(u2h2(wv[3][q].z), u2h2(ch.z), a3, false); \
            a0 = __builtin_amdgcn_fdot2(u2h2(wv[0][q].w), u2h2(ch.w), a0, false); \
            a1 = __builtin_amdgcn_fdot2(u2h2(wv[1][q].w), u2h2(ch.w), a1, false); \
            a2 = __builtin_amdgcn_fdot2(u2h2(wv[2][q].w), u2h2(ch.w), a2, false); \
            a3 = __builtin_amdgcn_fdot2(u2h2(wv[3][q].w), u2h2(ch.w), a3, false); \
        }                                                                   \
        float si = 1.f / (1.f + __expf(-a0));                               \
        float sf = 1.f / (1.f + __expf(-a1));                               \
        float tg = 1.f - 2.f / (__expf(2.f * a2) + 1.f);                    \
        float so = 1.f / (1.f + __expf(-a3));                               \
        c = sf * c + si * tg;                                               \
        float tc = 1.f - 2.f / (__expf(2.f * c) + 1.f);                     \
        float h = so * tc;                                                  \
        hs[j] = (_Float16)h;      /* in-order DS: visible to next step */   \
        *ep = h;                                                            \
        ep += H_;                                                           \
    }

    for (int t = 0; t < T_; t += 2) {
        STEP(gA, t + 2);
        STEP(gB, t + 3);
    }
#undef STEP
}

extern "C" void kernel_launch(void* const* d_in, const int* in_sizes, int n_in,
                              void* d_out, int out_size, void* d_ws, size_t ws_size,
                              hipStream_t stream) {
    if (n_in < 7 || in_sizes[0] != B_ * T_ * N_) return;

    const float* x    = (const float*)d_in[0];
    const float* aw   = (const float*)d_in[1];
    // d_in[2] (attn_b) provably cancels in the softmax — unused.
    const float* W_ih = (const float*)d_in[3];
    const float* W_hh = (const float*)d_in[4];
    const float* b_ih = (const float*)d_in[5];
    const float* b_hh = (const float*)d_in[6];

    float* iwp = (float*)d_out;                          // (B,T,N) f32
    float* enc = (float*)d_out + (size_t)B_ * T_ * N_;   // (B,T,H) f32

    size_t gx_bytes = (size_t)B_ * T_ * G_ * sizeof(_Float16);   // 33.5 MB
    _Float16* gatesx = (_Float16*)d_ws;
    uint4* wpack = (uint4*)((char*)d_ws + gx_bytes);             // 32 KB
    uint4* wih   = wpack + 2048;                                 // 64 KB (4096 entries)
    size_t need = gx_bytes + 2048 * sizeof(uint4) + 4096 * sizeof(uint4);
    if (ws_size < need) return;  // fail loudly rather than corrupt

    hipLaunchKernelGGL(k_wpack, dim3(8), dim3(256), 0, stream, W_hh, wpack);
    hipLaunchKernelGGL(k_wpackIH, dim3(16), dim3(256), 0, stream, W_ih, wih);
    hipLaunchKernelGGL(k_awgemm2, dim3(B_), dim3(256), 0, stream,
                       x, aw, wih, b_ih, b_hh, iwp, gatesx);
    hipLaunchKernelGGL(k_rnn10, dim3(B_), dim3(64), 0, stream,
                       gatesx, wpack, enc);
}

// Round 21
// 165.485 us; speedup vs baseline: 1.7793x; 1.0735x over previous
//
#include <hip/hip_runtime.h>
#include <hip/hip_fp16.h>
#include <cstdint>
#include <cstddef>

#define B_ 512
#define T_ 256
#define N_ 128
#define H_ 64
#define G_ 256  // 4H

typedef __attribute__((ext_vector_type(8))) short short8;
typedef __attribute__((ext_vector_type(4))) float f32x4;
typedef _Float16 half2_t __attribute__((ext_vector_type(2)));

static __device__ __forceinline__ float bf2f(unsigned short u) {
    union { unsigned int i; float f; } v;
    v.i = ((unsigned int)u) << 16;
    return v.f;
}
static __device__ __forceinline__ unsigned short f2bf(float f) {
    union { float f; unsigned int i; } v;
    v.f = f;
    unsigned int x = v.i;
    return (unsigned short)((x + 0x7fffu + ((x >> 16) & 1u)) >> 16);  // RNE
}
static __device__ __forceinline__ half2_t u2h2(unsigned int u) {
    union { unsigned int u; half2_t h; } v; v.u = u; return v.h;
}

// ---------------------------------------------------------------------------
// K0a: pack W_hh (f32 [4H][H]) -> wpack uint4 [4][8][64] (k_rnn lane order).
// ---------------------------------------------------------------------------
__global__ __launch_bounds__(256) void k_wpack(const float* __restrict__ W_hh,
                                               uint4* __restrict__ wpack) {
    int idx = blockIdx.x * 256 + threadIdx.x;   // 2048 entries
    if (idx >= 2048) return;
    int g = idx >> 9, q = (idx >> 6) & 7, j = idx & 63;
    const float* src = W_hh + ((size_t)(g * H_ + j)) * H_ + q * 8;
    float4 a = *(const float4*)(src);
    float4 b = *(const float4*)(src + 4);
    union { uint4 u; half2_t h[4]; } pk;
    pk.h[0] = (half2_t){(_Float16)a.x, (_Float16)a.y};
    pk.h[1] = (half2_t){(_Float16)a.z, (_Float16)a.w};
    pk.h[2] = (half2_t){(_Float16)b.x, (_Float16)b.y};
    pk.h[3] = (half2_t){(_Float16)b.z, (_Float16)b.w};
    wpack[idx] = pk.u;
}

// ---------------------------------------------------------------------------
// K0b: pack W_ih -> bf16 MFMA B-fragments, per-lane order (4096 entries).
// ---------------------------------------------------------------------------
__global__ __launch_bounds__(256) void k_wpackIH(const float* __restrict__ W_ih,
                                                 uint4* __restrict__ wp) {
    int idx = blockIdx.x * 256 + threadIdx.x;   // 4096 entries x 16B = 64 KB
    if (idx >= 4096) return;
    int lane = idx & 63;
    int rest = idx >> 6;            // w*16 + nt*4 + kc, 0..63
    int kc = rest & 3, nt = (rest >> 2) & 3, w = rest >> 4;
    int row = w * 64 + nt * 16 + (lane & 15);
    int kb  = kc * 32 + (lane >> 4) * 8;
    const float* src = W_ih + (size_t)row * N_ + kb;
    union { uint4 u; unsigned short s[8]; } pk;
    #pragma unroll
    for (int e = 0; e < 8; ++e) pk.s[e] = f2bf(src[e]);
    wp[idx] = pk.u;
}

// ---------------------------------------------------------------------------
// K1+K2: attention + weighting + GEMM (round-20 verified: ~38us).
// x staged to LDS bf16 in Phase A; W_ih fragments in 64 asm-resident VGPRs;
// LDS ~76 KB -> 2 blocks/CU; in-place weighting; 1 barrier/subtile.
// ---------------------------------------------------------------------------
__global__ __attribute__((amdgpu_flat_work_group_size(256, 256)))
__attribute__((amdgpu_waves_per_eu(2, 2)))
void k_awgemm2(const float* __restrict__ x,
               const float* __restrict__ attn_w,
               const uint4* __restrict__ wih,
               const float* __restrict__ b_ih,
               const float* __restrict__ b_hh,
               float* __restrict__ iw,
               _Float16* __restrict__ gatesx) {
    __shared__ __align__(16) unsigned short Xl[T_][136];  // bf16 x / wx, padded
    __shared__ float red2[8][128];
    __shared__ float bias[G_];
    __shared__ float aw_s[T_];
    __shared__ float a_s[N_];
    __shared__ float wred[4];
    const int tid = threadIdx.x;
    const int b = blockIdx.x;
    const int lane = tid & 63;
    const int w = tid >> 6;

    // W_ih B-fragments: 16 x asm dwordx4 = 64 forced-live VGPRs
    uint4 bfw[4][4];   // [nt][kc]
    #pragma unroll
    for (int nt = 0; nt < 4; ++nt) {
        #pragma unroll
        for (int kc = 0; kc < 4; ++kc) {
            unsigned voff = (unsigned)((((w * 4 + nt) * 4 + kc) * 64 + lane) << 4);
            asm volatile("global_load_dwordx4 %0, %1, %2"
                         : "=v"(bfw[nt][kc]) : "v"(voff), "s"(wih) : "memory");
        }
    }
    asm volatile("s_waitcnt vmcnt(0)" ::: "memory");

    bias[tid] = b_ih[tid] + b_hh[tid];
    aw_s[tid] = attn_w[2 * H_ + tid];
    __syncthreads();

    // ---- Phase A: attention dot + softmax; stage x -> Xl (bf16) ----
    const int n0 = (tid & 31) << 2;
    const int tg = tid >> 5;
    const float* xb = x + (size_t)b * (T_ * N_);
    {
        float p0 = 0.f, p1 = 0.f, p2 = 0.f, p3 = 0.f;
        for (int t = tg; t < T_; t += 8) {
            float4 v = *(const float4*)(xb + t * N_ + n0);
            float wt = aw_s[t];
            p0 += v.x * wt; p1 += v.y * wt; p2 += v.z * wt; p3 += v.w * wt;
            Xl[t][n0 + 0] = f2bf(v.x); Xl[t][n0 + 1] = f2bf(v.y);
            Xl[t][n0 + 2] = f2bf(v.z); Xl[t][n0 + 3] = f2bf(v.w);
        }
        red2[tg][n0 + 0] = p0; red2[tg][n0 + 1] = p1;
        red2[tg][n0 + 2] = p2; red2[tg][n0 + 3] = p3;
    }
    __syncthreads();
    {
        float s = 0.f;
        if (tid < 128) {
            #pragma unroll
            for (int g = 0; g < 8; ++g) s += red2[g][tid];
        }
        float m = (tid < 128) ? s : -1e30f;
        #pragma unroll
        for (int d = 1; d < 64; d <<= 1) m = fmaxf(m, __shfl_xor(m, d));
        if ((tid & 63) == 0) wred[tid >> 6] = m;
        __syncthreads();
        m = fmaxf(wred[0], wred[1]);
        __syncthreads();
        float e = (tid < 128) ? __expf(s - m) : 0.f;
        float z = e;
        #pragma unroll
        for (int d = 1; d < 64; d <<= 1) z += __shfl_xor(z, d);
        if ((tid & 63) == 0) wred[tid >> 6] = z;
        __syncthreads();
        z = wred[0] + wred[1];
        if (tid < 128) a_s[tid] = e / z;
    }
    __syncthreads();   // a_s + all Xl writes visible

    // ---- Phase B: in-place weighting + MFMA (B from registers) ----
    const int lr = lane & 15;
    const int lk = (lane >> 4) << 3;
    const int gc0 = w << 6;
    const int orow = (lane >> 4) << 2;

    for (int st = 0; st < 8; ++st) {
        const int r0g = b * T_ + st * 32;
        for (int q = tid; q < 32 * 32; q += 256) {
            int r = q >> 5, c4 = (q & 31) << 2;
            int row = st * 32 + r;
            ushort4 xv = *(const ushort4*)(&Xl[row][c4]);
            float4 wv4;
            wv4.x = a_s[c4 + 0] * bf2f(xv.x); wv4.y = a_s[c4 + 1] * bf2f(xv.y);
            wv4.z = a_s[c4 + 2] * bf2f(xv.z); wv4.w = a_s[c4 + 3] * bf2f(xv.w);
            *(float4*)(iw + (size_t)(r0g + r) * N_ + c4) = wv4;   // output 0
            Xl[row][c4 + 0] = f2bf(wv4.x); Xl[row][c4 + 1] = f2bf(wv4.y);
            Xl[row][c4 + 2] = f2bf(wv4.z); Xl[row][c4 + 3] = f2bf(wv4.w);
        }
        __syncthreads();

        f32x4 acc[2][4];
        #pragma unroll
        for (int mt = 0; mt < 2; ++mt)
            #pragma unroll
            for (int nt = 0; nt < 4; ++nt)
                acc[mt][nt] = (f32x4){0.f, 0.f, 0.f, 0.f};

        #pragma unroll
        for (int kc = 0; kc < 4; ++kc) {
            short8 af0 = *(const short8*)(&Xl[st * 32 + lr][kc * 32 + lk]);
            short8 af1 = *(const short8*)(&Xl[st * 32 + 16 + lr][kc * 32 + lk]);
            #pragma unroll
            for (int nt = 0; nt < 4; ++nt) {
                short8 bfv = *(const short8*)(&bfw[nt][kc]);
                acc[0][nt] = __builtin_amdgcn_mfma_f32_16x16x32_bf16(af0, bfv, acc[0][nt], 0, 0, 0);
                acc[1][nt] = __builtin_amdgcn_mfma_f32_16x16x32_bf16(af1, bfv, acc[1][nt], 0, 0, 0);
            }
        }
        #pragma unroll
        for (int mt = 0; mt < 2; ++mt) {
            #pragma unroll
            for (int nt = 0; nt < 4; ++nt) {
                int col = gc0 + nt * 16 + lr;
                float bs = bias[col];
                int cell = col & 63, qg = col >> 6;
                #pragma unroll
                for (int rg = 0; rg < 4; ++rg) {
                    int rr = r0g + mt * 16 + orow + rg;
                    gatesx[((size_t)rr * H_ + cell) * 4 + qg] =
                        (_Float16)(acc[mt][nt][rg] + bs);
                }
            }
        }
    }
}

// ---------------------------------------------------------------------------
// K3: LSTM recurrence — k_rnn10 + (a) 4 partial accumulators per gate and
// (b) rcp-based activations.
// Rationale: the 133us plateau survived two broadcast mechanisms; the one
// untested combo is partial-accs on the LDS path (round 11 tested them only
// with readlane, whose SGPR hazards could mask the dot-chain gain). Each
// gate's dot was a 32-deep dependent fdot2 chain (4-way ILP); now 16
// independent 8-deep chains (component e -> chain e), combined in 8 adds.
// rcpf: sigmoid/tanh divisions -> v_rcp_f32 (1 inst vs ~4), ~15 inst/step off.
// ---------------------------------------------------------------------------
__global__ __attribute__((amdgpu_flat_work_group_size(64, 64)))
__attribute__((amdgpu_waves_per_eu(1, 1)))
void k_rnn17(const _Float16* __restrict__ gatesx,
             const uint4* __restrict__ wpack,
             float* __restrict__ enc) {
    __shared__ __align__(16) _Float16 hs[H_];   // h_t (f16), 128 B
    const int j = threadIdx.x;   // cell index
    const int b = blockIdx.x;

    uint4 wv[4][8];
    #pragma unroll
    for (int g = 0; g < 4; ++g) {
        #pragma unroll
        for (int q = 0; q < 8; ++q) {
            unsigned voff = (unsigned)((((g << 3) + q) * 64 + j) << 4);
            asm volatile("global_load_dwordx4 %0, %1, %2"
                         : "=v"(wv[g][q]) : "v"(voff), "s"(wpack) : "memory");
        }
    }
    asm volatile("s_waitcnt vmcnt(0)" ::: "memory");

    hs[j] = (_Float16)0.f;     // h_{-1} = 0 (single wave: DS in-order)
    float c = 0.f;

    const _Float16* gx = gatesx + ((size_t)b * T_ * H_ + j) * 4;
    float* ep = enc + (size_t)b * T_ * H_ + j;

    uint2 gA = *(const uint2*)(gx);            // t = 0
    uint2 gB = *(const uint2*)(gx + G_);       // t = 1

    // component e of quad q feeds partial chain e of each gate:
#define DOTC(Q, E, CHC)                                                     \
        do {                                                                \
            half2_t hh_ = u2h2(CHC);                                        \
            pa[0][E] = __builtin_amdgcn_fdot2(u2h2(wv[0][Q].CHC_X), hh_, pa[0][E], false); \
            pa[1][E] = __builtin_amdgcn_fdot2(u2h2(wv[1][Q].CHC_X), hh_, pa[1][E], false); \
            pa[2][E] = __builtin_amdgcn_fdot2(u2h2(wv[2][Q].CHC_X), hh_, pa[2][E], false); \
            pa[3][E] = __builtin_amdgcn_fdot2(u2h2(wv[3][Q].CHC_X), hh_, pa[3][E], false); \
        } while (0)

#define SIG(x)  (__builtin_amdgcn_rcpf(1.f + __expf(-(x))))
#define TANH(x) (1.f - 2.f * __builtin_amdgcn_rcpf(__expf(2.f * (x)) + 1.f))

#define STEP(GREG, TNEXT)                                                   \
    {                                                                       \
        half2_t gif = u2h2(GREG.x), ggo = u2h2(GREG.y);                     \
        float pa[4][4];                                                     \
        pa[0][0] = (float)gif.x; pa[1][0] = (float)gif.y;                   \
        pa[2][0] = (float)ggo.x; pa[3][0] = (float)ggo.y;                   \
        _Pragma("unroll")                                                   \
        for (int g_ = 0; g_ < 4; ++g_) {                                    \
            pa[g_][1] = 0.f; pa[g_][2] = 0.f; pa[g_][3] = 0.f;              \
        }                                                                   \
        int tn_ = (TNEXT) < T_ ? (TNEXT) : (T_ - 1);                        \
        GREG = *(const uint2*)(gx + (size_t)tn_ * G_);                      \
        const uint4* hv4 = (const uint4*)hs;                                \
        _Pragma("unroll")                                                   \
        for (int q = 0; q < 8; ++q) {                                       \
            uint4 ch = hv4[q];        /* uniform addr -> broadcast */       \
            pa[0][0] = __builtin_amdgcn_fdot2(u2h2(wv[0][q].x), u2h2(ch.x), pa[0][0], false); \
            pa[1][0] = __builtin_amdgcn_fdot2(u2h2(wv[1][q].x), u2h2(ch.x), pa[1][0], false); \
            pa[2][0] = __builtin_amdgcn_fdot2(u2h2(wv[2][q].x), u2h2(ch.x), pa[2][0], false); \
            pa[3][0] = __builtin_amdgcn_fdot2(u2h2(wv[3][q].x), u2h2(ch.x), pa[3][0], false); \
            pa[0][1] = __builtin_amdgcn_fdot2(u2h2(wv[0][q].y), u2h2(ch.y), pa[0][1], false); \
            pa[1][1] = __builtin_amdgcn_fdot2(u2h2(wv[1][q].y), u2h2(ch.y), pa[1][1], false); \
            pa[2][1] = __builtin_amdgcn_fdot2(u2h2(wv[2][q].y), u2h2(ch.y), pa[2][1], false); \
            pa[3][1] = __builtin_amdgcn_fdot2(u2h2(wv[3][q].y), u2h2(ch.y), pa[3][1], false); \
            pa[0][2] = __builtin_amdgcn_fdot2(u2h2(wv[0][q].z), u2h2(ch.z), pa[0][2], false); \
            pa[1][2] = __builtin_amdgcn_fdot2(u2h2(wv[1][q].z), u2h2(ch.z), pa[1][2], false); \
            pa[2][2] = __builtin_amdgcn_fdot2(u2h2(wv[2][q].z), u2h2(ch.z), pa[2][2], false); \
            pa[3][2] = __builtin_amdgcn_fdot2(u2h2(wv[3][q].z), u2h2(ch.z), pa[3][2], false); \
            pa[0][3] = __builtin_amdgcn_fdot2(u2h2(wv[0][q].w), u2h2(ch.w), pa[0][3], false); \
            pa[1][3] = __builtin_amdgcn_fdot2(u2h2(wv[1][q].w), u2h2(ch.w), pa[1][3], false); \
            pa[2][3] = __builtin_amdgcn_fdot2(u2h2(wv[2][q].w), u2h2(ch.w), pa[2][3], false); \
            pa[3][3] = __builtin_amdgcn_fdot2(u2h2(wv[3][q].w), u2h2(ch.w), pa[3][3], false); \
        }                                                                   \
        float a0 = (pa[0][0] + pa[0][1]) + (pa[0][2] + pa[0][3]);           \
        float a1 = (pa[1][0] + pa[1][1]) + (pa[1][2] + pa[1][3]);           \
        float a2 = (pa[2][0] + pa[2][1]) + (pa[2][2] + pa[2][3]);           \
        float a3 = (pa[3][0] + pa[3][1]) + (pa[3][2] + pa[3][3]);           \
        float si = SIG(a0);                                                 \
        float sf = SIG(a1);                                                 \
        float tg = TANH(a2);                                                \
        float so = SIG(a3);                                                 \
        c = sf * c + si * tg;                                               \
        float tc = TANH(c);                                                 \
        float h = so * tc;                                                  \
        hs[j] = (_Float16)h;      /* in-order DS: visible to next step */   \
        *ep = h;                                                            \
        ep += H_;                                                           \
    }

    for (int t = 0; t < T_; t += 2) {
        STEP(gA, t + 2);
        STEP(gB, t + 3);
    }
#undef STEP
#undef SIG
#undef TANH
#undef DOTC
}

extern "C" void kernel_launch(void* const* d_in, const int* in_sizes, int n_in,
                              void* d_out, int out_size, void* d_ws, size_t ws_size,
                              hipStream_t stream) {
    if (n_in < 7 || in_sizes[0] != B_ * T_ * N_) return;

    const float* x    = (const float*)d_in[0];
    const float* aw   = (const float*)d_in[1];
    // d_in[2] (attn_b) provably cancels in the softmax — unused.
    const float* W_ih = (const float*)d_in[3];
    const float* W_hh = (const float*)d_in[4];
    const float* b_ih = (const float*)d_in[5];
    const float* b_hh = (const float*)d_in[6];

    float* iwp = (float*)d_out;                          // (B,T,N) f32
    float* enc = (float*)d_out + (size_t)B_ * T_ * N_;   // (B,T,H) f32

    size_t gx_bytes = (size_t)B_ * T_ * G_ * sizeof(_Float16);   // 33.5 MB
    _Float16* gatesx = (_Float16*)d_ws;
    uint4* wpack = (uint4*)((char*)d_ws + gx_bytes);             // 32 KB
    uint4* wih   = wpack + 2048;                                 // 64 KB
    size_t need = gx_bytes + 2048 * sizeof(uint4) + 4096 * sizeof(uint4);
    if (ws_size < need) return;  // fail loudly rather than corrupt

    hipLaunchKernelGGL(k_wpack, dim3(8), dim3(256), 0, stream, W_hh, wpack);
    hipLaunchKernelGGL(k_wpackIH, dim3(16), dim3(256), 0, stream, W_ih, wih);
    hipLaunchKernelGGL(k_awgemm2, dim3(B_), dim3(256), 0, stream,
                       x, aw, wih, b_ih, b_hh, iwp, gatesx);
    hipLaunchKernelGGL(k_rnn17, dim3(B_), dim3(64), 0, stream,
                       gatesx, wpack, enc);
}